// Round 4
// baseline (1608.702 us; speedup 1.0000x reference)
//
#include <hip/hip_runtime.h>
#include <cstdint>
#include <cmath>

// Problem: z[32768,512] f32, emb[4096,512] f32
#define N_ROWS 32768
#define DIM    512
#define KCODES 4096
#define SPLITS 4
#define CPS    (KCODES / SPLITS)   // 1024 codes per split
#define KCL    (CPS / 64)          // 16 code-chunks per split
#define BM     128                 // rows per block = 4 waves x 32
#define TAU    2e-3f               // score-gap threshold (~17 sigma of f16 noise)

typedef _Float16 f16x8 __attribute__((ext_vector_type(8)));
typedef float    f32x4 __attribute__((ext_vector_type(4)));

// ---- ws layout (float units) ----
// [0, 1048576): f16 codebook image, 256 tiles x 16KB (4 MB)
#define OFF_NH  1048576                        // negHalf[4096]
#define OFF_EN  (OFF_NH + KCODES)              // Enp[4096] (np-exact ||e||^2)
#define OFF_PS  (OFF_EN + KCODES)              // pscore[SPLITS][N_ROWS][3]
#define OFF_PI  (OFF_PS + SPLITS * N_ROWS * 3) // pidx   [SPLITS][N_ROWS][3]
#define OFF_BI  (OFF_PI + SPLITS * N_ROWS * 3) // best idx[N_ROWS]
#define OFF_BS  (OFF_BI + N_ROWS)              // blockSums[2048]

__device__ __forceinline__ bool lexGT(float v1, int i1, float v2, int i2) {
  return (v1 > v2) || (v1 == v2 && i1 < i2);
}

__device__ __forceinline__ void gload16(const void* g, void* l) {
  __builtin_amdgcn_global_load_lds(
      (const __attribute__((address_space(1))) unsigned int*)g,
      (__attribute__((address_space(3))) unsigned int*)l, 16, 0, 0);
}

// ---- numpy fp32 bit-exact helpers (verified passing rounds 2-3) ----
__device__ float np_sumsq_512(const float* __restrict__ a) {
#pragma clang fp contract(off)
  float B[4];
#pragma unroll
  for (int t = 0; t < 4; ++t) {
    const float* p = a + t * 128;
    float r[8];
#pragma unroll
    for (int j = 0; j < 8; ++j) { float x = p[j]; r[j] = x * x; }
    for (int i = 8; i < 128; i += 8) {
#pragma unroll
      for (int j = 0; j < 8; ++j) {
        float x = p[i + j];
        float sq = x * x;
        r[j] = r[j] + sq;
      }
    }
    B[t] = ((r[0] + r[1]) + (r[2] + r[3])) + ((r[4] + r[5]) + (r[6] + r[7]));
  }
  return (B[0] + B[1]) + (B[2] + B[3]);
}

__device__ float np_dot_512(const float* __restrict__ x, const float* __restrict__ y) {
  float acc = 0.0f;
  for (int d = 0; d < DIM; ++d) acc = fmaf(x[d], y[d], acc);
  return acc;
}

// ---- prep 1: np-exact ||e||^2 per code (one thread per code) ----
__global__ __launch_bounds__(256) void vq_prep_e(const float* __restrict__ emb,
                                                 float* __restrict__ Enp,
                                                 float* __restrict__ negHalf) {
  int k = blockIdx.x * 256 + threadIdx.x;
  float E = np_sumsq_512(emb + (size_t)k * DIM);
  Enp[k] = E;
  negHalf[k] = -0.5f * E;
}

// ---- prep 2: f16 codebook image in MFMA fragment-block order ----
// tile T = kcg*4+dci (16KB): 16 fragment-blocks fb=ks*4+ct (1KB), lane l at l*16B,
// lane (tl=l&15, gh=l>>4) holds code (kcg*64+ct*16+tl), d = dci*128+(ks*4+gh)*8 ..+8
__global__ __launch_bounds__(256) void vq_prep_img(const float* __restrict__ emb,
                                                   f16x8* __restrict__ img) {
  int gid = blockIdx.x * 256 + threadIdx.x;   // [0, 262144)
  int k = gid >> 6, seg = gid & 63;
  int dci = seg >> 4, s = seg & 15;
  int kcg = k >> 6, r = k & 63;
  int ct = r >> 4, tl = r & 15;
  int ks = s >> 2, gh = s & 3;
  int lane = gh * 16 + tl;
  const float* ep = emb + (size_t)k * DIM + dci * 128 + s * 8;
  float4 a = *(const float4*)ep;
  float4 b = *(const float4*)(ep + 4);
  float f[8] = {a.x, a.y, a.z, a.w, b.x, b.y, b.z, b.w};
  f16x8 h;
#pragma unroll
  for (int j = 0; j < 8; ++j) h[j] = (_Float16)f[j];
  img[(size_t)(kcg * 4 + dci) * 1024 + (ks * 4 + ct) * 64 + lane] = h;
}

// ---- main: per-block 128 rows x 1024 codes, top-3 per split ----
__global__ __launch_bounds__(256, 4) void vq_main(const float* __restrict__ z,
                                                  const f16x8* __restrict__ img,
                                                  const float* __restrict__ negHalf,
                                                  float* __restrict__ pscore,
                                                  int* __restrict__ pidx) {
  __shared__ f16x8 EHs[2048];   // 2 x 16KB double buffer

  const int tid  = threadIdx.x;
  const int w    = tid >> 6;
  const int lane = tid & 63;
  const int tl   = lane & 15;
  const int gh   = lane >> 4;
  const int bid  = blockIdx.x;
  const int rb   = bid >> 2;       // row-block 0..255
  const int sp   = bid & 3;        // code split 0..3
  const int m0   = rb * BM;

  // resident A: 2 row-tiles x 16 K-chunks of f16x8 (zh only; e-conversion noise
  // dominates anyway, TAU-refine covers it)
  f16x8 zh[2][16];
#pragma unroll
  for (int rt = 0; rt < 2; ++rt) {
    const float* zp = z + (size_t)(m0 + w * 32 + rt * 16 + tl) * DIM + gh * 8;
#pragma unroll
    for (int c = 0; c < 16; ++c) {
      float4 a = *(const float4*)(zp + c * 32);
      float4 b = *(const float4*)(zp + c * 32 + 4);
      float f[8] = {a.x, a.y, a.z, a.w, b.x, b.y, b.z, b.w};
      f16x8 h;
#pragma unroll
      for (int j = 0; j < 8; ++j) h[j] = (_Float16)f[j];
      zh[rt][c] = h;
    }
  }

  float R1[8], R2[8], R3[8];
  int   I1[8], I2[8], I3[8];
#pragma unroll
  for (int i = 0; i < 8; ++i) {
    R1[i] = -INFINITY; R2[i] = -INFINITY; R3[i] = -INFINITY;
    I1[i] = 0x7fffffff; I2[i] = 0x7fffffff; I3[i] = 0x7fffffff;
  }

  const f16x8* tbase = img + (size_t)sp * 64 * 1024;  // this split's 64 tiles

  // prologue: stage tile 0 into buf 0 (each wave its 4KB quarter)
  {
    const char* g = (const char*)tbase + w * 4096 + lane * 16;
    char* l = (char*)EHs + w * 4096;
#pragma unroll
    for (int i = 0; i < 4; ++i) gload16(g + i * 1024, l + i * 1024);
  }
  __syncthreads();

  for (int kcl = 0; kcl < KCL; ++kcl) {
    f32x4 acc[2][4];
#pragma unroll
    for (int ct = 0; ct < 4; ++ct) {
      float nh = negHalf[sp * CPS + kcl * 64 + ct * 16 + tl];
      acc[0][ct] = (f32x4){nh, nh, nh, nh};
      acc[1][ct] = (f32x4){nh, nh, nh, nh};
    }

#pragma unroll
    for (int dci = 0; dci < 4; ++dci) {
      const int t = kcl * 4 + dci;
      const int cur = t & 1;
      if (t + 1 < 64) {  // stage next tile into the other buffer
        const char* g = (const char*)(tbase + (size_t)(t + 1) * 1024) + w * 4096 + lane * 16;
        char* l = (char*)EHs + (cur ^ 1) * 16384 + w * 4096;
#pragma unroll
        for (int i = 0; i < 4; ++i) gload16(g + i * 1024, l + i * 1024);
      }
      const f16x8* B = EHs + cur * 1024;
#pragma unroll
      for (int ks = 0; ks < 4; ++ks) {
        f16x8 bf0 = B[(ks * 4 + 0) * 64 + lane];
        f16x8 bf1 = B[(ks * 4 + 1) * 64 + lane];
        f16x8 bf2 = B[(ks * 4 + 2) * 64 + lane];
        f16x8 bf3 = B[(ks * 4 + 3) * 64 + lane];
        acc[0][0] = __builtin_amdgcn_mfma_f32_16x16x32_f16(zh[0][dci * 4 + ks], bf0, acc[0][0], 0, 0, 0);
        acc[1][0] = __builtin_amdgcn_mfma_f32_16x16x32_f16(zh[1][dci * 4 + ks], bf0, acc[1][0], 0, 0, 0);
        acc[0][1] = __builtin_amdgcn_mfma_f32_16x16x32_f16(zh[0][dci * 4 + ks], bf1, acc[0][1], 0, 0, 0);
        acc[1][1] = __builtin_amdgcn_mfma_f32_16x16x32_f16(zh[1][dci * 4 + ks], bf1, acc[1][1], 0, 0, 0);
        acc[0][2] = __builtin_amdgcn_mfma_f32_16x16x32_f16(zh[0][dci * 4 + ks], bf2, acc[0][2], 0, 0, 0);
        acc[1][2] = __builtin_amdgcn_mfma_f32_16x16x32_f16(zh[1][dci * 4 + ks], bf2, acc[1][2], 0, 0, 0);
        acc[0][3] = __builtin_amdgcn_mfma_f32_16x16x32_f16(zh[0][dci * 4 + ks], bf3, acc[0][3], 0, 0, 0);
        acc[1][3] = __builtin_amdgcn_mfma_f32_16x16x32_f16(zh[1][dci * 4 + ks], bf3, acc[1][3], 0, 0, 0);
      }
      __syncthreads();
    }

    // merge the chunk's candidates (increasing code index -> strict '>' keeps
    // lowest index on exact ties)
#pragma unroll
    for (int rt = 0; rt < 2; ++rt)
#pragma unroll
      for (int ct = 0; ct < 4; ++ct) {
        int c = sp * CPS + kcl * 64 + ct * 16 + tl;
#pragma unroll
        for (int i = 0; i < 4; ++i) {
          int r8 = rt * 4 + i;
          float v = acc[rt][ct][i];
          if (v > R3[r8]) {
            if (v > R1[r8]) {
              R3[r8] = R2[r8]; I3[r8] = I2[r8];
              R2[r8] = R1[r8]; I2[r8] = I1[r8];
              R1[r8] = v;      I1[r8] = c;
            } else if (v > R2[r8]) {
              R3[r8] = R2[r8]; I3[r8] = I2[r8];
              R2[r8] = v;      I2[r8] = c;
            } else {
              R3[r8] = v;      I3[r8] = c;
            }
          }
        }
      }
  }

  // butterfly top-3 merge across the 16 tl-lanes (disjoint code sets)
#pragma unroll
  for (int m = 1; m < 16; m <<= 1) {
#pragma unroll
    for (int i = 0; i < 8; ++i) {
      float b1 = __shfl_xor(R1[i], m, 16); int j1 = __shfl_xor(I1[i], m, 16);
      float b2 = __shfl_xor(R2[i], m, 16); int j2 = __shfl_xor(I2[i], m, 16);
      float b3 = __shfl_xor(R3[i], m, 16); int j3 = __shfl_xor(I3[i], m, 16);
#pragma unroll
      for (int q = 0; q < 3; ++q) {
        float v = (q == 0) ? b1 : (q == 1) ? b2 : b3;
        int   c = (q == 0) ? j1 : (q == 1) ? j2 : j3;
        if (lexGT(v, c, R3[i], I3[i])) {
          if (lexGT(v, c, R1[i], I1[i])) {
            R3[i] = R2[i]; I3[i] = I2[i];
            R2[i] = R1[i]; I2[i] = I1[i];
            R1[i] = v;     I1[i] = c;
          } else if (lexGT(v, c, R2[i], I2[i])) {
            R3[i] = R2[i]; I3[i] = I2[i];
            R2[i] = v;     I2[i] = c;
          } else {
            R3[i] = v;     I3[i] = c;
          }
        }
      }
    }
  }

  if (tl == 0) {
#pragma unroll
    for (int i = 0; i < 8; ++i) {
      int row = m0 + w * 32 + (i >> 2) * 16 + gh * 4 + (i & 3);
      size_t pb = ((size_t)sp * N_ROWS + row) * 3;
      pscore[pb + 0] = R1[i]; pidx[pb + 0] = I1[i];
      pscore[pb + 1] = R2[i]; pidx[pb + 1] = I2[i];
      pscore[pb + 2] = R3[i]; pidx[pb + 2] = I3[i];
    }
  }
}

// ---- merge 4 split top-3s per row; np-exact refine on near-ties ----
__global__ __launch_bounds__(256) void vq_merge(const float* __restrict__ z,
                                                const float* __restrict__ emb,
                                                const float* __restrict__ Enp,
                                                const float* __restrict__ pscore,
                                                const int* __restrict__ pidx,
                                                int* __restrict__ bi,
                                                float* __restrict__ outIdx) {
  int row = blockIdx.x * 256 + threadIdx.x;
  float vs[12]; int cs[12];
#pragma unroll
  for (int s = 0; s < 4; ++s) {
    size_t pb = ((size_t)s * N_ROWS + row) * 3;
#pragma unroll
    for (int q = 0; q < 3; ++q) { vs[s * 3 + q] = pscore[pb + q]; cs[s * 3 + q] = pidx[pb + q]; }
  }
  float R1 = -INFINITY, R2 = -INFINITY; int i1 = 0x7fffffff;
#pragma unroll
  for (int j = 0; j < 12; ++j) {
    float v = vs[j]; int c = cs[j];
    if (lexGT(v, c, R1, i1)) { R2 = R1; R1 = v; i1 = c; }
    else if (v > R2) { R2 = v; }
  }
  int best = i1;
  if (R1 - R2 < TAU) {
#pragma clang fp contract(off)
    const float* zr = z + (size_t)row * DIM;
    float S = np_sumsq_512(zr);
    float bd = INFINITY; int bc = 0x7fffffff;
#pragma unroll 1
    for (int j = 0; j < 12; ++j) {
      if (R1 - vs[j] < TAU) {
        int c = cs[j];
        float D = np_dot_512(zr, emb + (size_t)c * DIM);
        float t = S + Enp[c];
        float d = t - 2.0f * D;
        if (d < bd || (d == bd && c < bc)) { bd = d; bc = c; }
      }
    }
    best = bc;
  }
  bi[row] = best;
  outIdx[row] = (float)best;
}

// ---- epilogue: gather e[best], write quantized, loss partials ----
__global__ __launch_bounds__(256) void vq_epi(const float* __restrict__ z,
                                              const float* __restrict__ emb,
                                              const int* __restrict__ bi,
                                              float* __restrict__ out,
                                              float* __restrict__ blockSums) {
  __shared__ float wred[4];
  int tid = threadIdx.x;
  int g = tid >> 4, tl = tid & 15;
  int row = blockIdx.x * 16 + g;
  const float* zr = z + (size_t)row * DIM;
  const float* er = emb + (size_t)bi[row] * DIM;
  float* oq = out + 1 + (size_t)row * DIM;
  float ls = 0.f;
#pragma unroll
  for (int j = 0; j < 8; ++j) {
    int d0 = (j * 16 + tl) * 4;
    float4 e = *(const float4*)(er + d0);
    float4 zz = *(const float4*)(zr + d0);
    float dx = e.x - zz.x, dy = e.y - zz.y, dz = e.z - zz.z, dw = e.w - zz.w;
    ls = fmaf(dx, dx, ls); ls = fmaf(dy, dy, ls);
    ls = fmaf(dz, dz, ls); ls = fmaf(dw, dw, ls);
    oq[d0 + 0] = e.x; oq[d0 + 1] = e.y; oq[d0 + 2] = e.z; oq[d0 + 3] = e.w;
  }
#pragma unroll
  for (int m = 1; m < 64; m <<= 1) ls += __shfl_xor(ls, m, 64);
  if ((tid & 63) == 0) wred[tid >> 6] = ls;
  __syncthreads();
  if (tid == 0) blockSums[blockIdx.x] = wred[0] + wred[1] + wred[2] + wred[3];
}

// loss = 1.25 * mean((q-z)^2); KL factor 0. 2048 partials.
__global__ __launch_bounds__(256) void vq_final(const float* __restrict__ blockSums,
                                                float* __restrict__ out) {
  __shared__ float red[256];
  int t = threadIdx.x;
  float s = 0.f;
#pragma unroll
  for (int i = 0; i < 8; ++i) s += blockSums[t + i * 256];
  red[t] = s;
  __syncthreads();
  for (int k = 128; k > 0; k >>= 1) {
    if (t < k) red[t] += red[t + k];
    __syncthreads();
  }
  if (t == 0) out[0] = red[0] * (1.25f / 16777216.0f);
}

extern "C" void kernel_launch(void* const* d_in, const int* in_sizes, int n_in,
                              void* d_out, int out_size, void* d_ws, size_t ws_size,
                              hipStream_t stream) {
  const float* z   = (const float*)d_in[0];
  const float* emb = (const float*)d_in[1];
  float* out  = (float*)d_out;
  float* wsf  = (float*)d_ws;
  f16x8* img      = (f16x8*)d_ws;
  float* negHalf  = wsf + OFF_NH;
  float* Enp      = wsf + OFF_EN;
  float* pscore   = wsf + OFF_PS;
  int*   pidx     = (int*)(wsf + OFF_PI);
  int*   bi       = (int*)(wsf + OFF_BI);
  float* bsums    = wsf + OFF_BS;
  float* outIdx   = out + 1 + (size_t)N_ROWS * DIM;
  (void)in_sizes; (void)n_in; (void)out_size; (void)ws_size;

  vq_prep_e  <<<KCODES / 256, 256, 0, stream>>>(emb, Enp, negHalf);
  vq_prep_img<<<1024, 256, 0, stream>>>(emb, img);
  vq_main    <<<1024, 256, 0, stream>>>(z, img, negHalf, pscore, pidx);
  vq_merge   <<<N_ROWS / 256, 256, 0, stream>>>(z, emb, Enp, pscore, pidx, bi, outIdx);
  vq_epi     <<<N_ROWS / 16, 256, 0, stream>>>(z, emb, bi, out, bsums);
  vq_final   <<<1, 256, 0, stream>>>(bsums, out);
}

// Round 5
// 389.883 us; speedup vs baseline: 4.1261x; 4.1261x over previous
//
#include <hip/hip_runtime.h>
#include <cstdint>
#include <cmath>

// Problem: z[32768,512] f32, emb[4096,512] f32
#define N_ROWS 32768
#define DIM    512
#define KCODES 4096
#define SPLITS 4
#define CPS    (KCODES / SPLITS)   // 1024 codes per split
#define KCL    (CPS / 64)          // 16 code-chunks per split
#define BM     128                 // rows per block = 4 waves x 32
#define TAU    2e-3f               // score-gap threshold (~6 sigma of f16 noise)

typedef _Float16 f16x8 __attribute__((ext_vector_type(8)));
typedef float    f32x4 __attribute__((ext_vector_type(4)));

// ---- ws layout (float units) ----
// [0, 1048576): f16 codebook image, 256 tiles x 16KB (4 MB)
#define OFF_NH  1048576                        // negHalf[4096]
#define OFF_EN  (OFF_NH + KCODES)              // Enp[4096] (np-exact ||e||^2)
#define OFF_PS  (OFF_EN + KCODES)              // pscore[SPLITS][N_ROWS][3]
#define OFF_PI  (OFF_PS + SPLITS * N_ROWS * 3) // pidx   [SPLITS][N_ROWS][3]
#define OFF_BI  (OFF_PI + SPLITS * N_ROWS * 3) // best idx[N_ROWS]
#define OFF_BS  (OFF_BI + N_ROWS)              // blockSums[2048]

__device__ __forceinline__ bool lexGT(float v1, int i1, float v2, int i2) {
  return (v1 > v2) || (v1 == v2 && i1 < i2);
}

__device__ __forceinline__ void gload16(const void* g, void* l) {
  __builtin_amdgcn_global_load_lds(
      (const __attribute__((address_space(1))) unsigned int*)g,
      (__attribute__((address_space(3))) unsigned int*)l, 16, 0, 0);
}

// ---- numpy fp32 bit-exact helpers (verified passing rounds 2-4) ----
__device__ float np_sumsq_512(const float* __restrict__ a) {
#pragma clang fp contract(off)
  float B[4];
#pragma unroll
  for (int t = 0; t < 4; ++t) {
    const float* p = a + t * 128;
    float r[8];
#pragma unroll
    for (int j = 0; j < 8; ++j) { float x = p[j]; r[j] = x * x; }
    for (int i = 8; i < 128; i += 8) {
#pragma unroll
      for (int j = 0; j < 8; ++j) {
        float x = p[i + j];
        float sq = x * x;
        r[j] = r[j] + sq;
      }
    }
    B[t] = ((r[0] + r[1]) + (r[2] + r[3])) + ((r[4] + r[5]) + (r[6] + r[7]));
  }
  return (B[0] + B[1]) + (B[2] + B[3]);
}

__device__ float np_dot_512(const float* __restrict__ x, const float* __restrict__ y) {
  float acc = 0.0f;
  for (int d = 0; d < DIM; ++d) acc = fmaf(x[d], y[d], acc);
  return acc;
}

// ---- prep 1: np-exact ||e||^2 per code (one thread per code) ----
__global__ __launch_bounds__(256) void vq_prep_e(const float* __restrict__ emb,
                                                 float* __restrict__ Enp,
                                                 float* __restrict__ negHalf) {
  int k = blockIdx.x * 256 + threadIdx.x;
  float E = np_sumsq_512(emb + (size_t)k * DIM);
  Enp[k] = E;
  negHalf[k] = -0.5f * E;
}

// ---- prep 2: f16 codebook image in MFMA fragment-block order ----
// tile T = kcg*4+dci (16KB): 16 fragment-blocks fb=ks*4+ct (1KB), lane l at l*16B,
// lane (tl=l&15, gh=l>>4) holds code (kcg*64+ct*16+tl), d = dci*128+(ks*4+gh)*8 ..+8
__global__ __launch_bounds__(256) void vq_prep_img(const float* __restrict__ emb,
                                                   f16x8* __restrict__ img) {
  int gid = blockIdx.x * 256 + threadIdx.x;   // [0, 262144)
  int k = gid >> 6, seg = gid & 63;
  int dci = seg >> 4, s = seg & 15;
  int kcg = k >> 6, r = k & 63;
  int ct = r >> 4, tl = r & 15;
  int ks = s >> 2, gh = s & 3;
  int lane = gh * 16 + tl;
  const float* ep = emb + (size_t)k * DIM + dci * 128 + s * 8;
  float4 a = *(const float4*)ep;
  float4 b = *(const float4*)(ep + 4);
  float f[8] = {a.x, a.y, a.z, a.w, b.x, b.y, b.z, b.w};
  f16x8 h;
#pragma unroll
  for (int j = 0; j < 8; ++j) h[j] = (_Float16)f[j];
  img[(size_t)(kcg * 4 + dci) * 1024 + (ks * 4 + ct) * 64 + lane] = h;
}

// ---- main: per-block 128 rows x 1024 codes, top-3 per split ----
// launch_bounds(256,2): 2 blocks/CU, VGPR cap 256 (round-4's (256,4) forced
// 64 VGPR -> 2GB scratch spill traffic; this kernel needs ~240).
__global__ __launch_bounds__(256, 2) void vq_main(const float* __restrict__ z,
                                                  const f16x8* __restrict__ img,
                                                  const float* __restrict__ negHalf,
                                                  float* __restrict__ pscore,
                                                  int* __restrict__ pidx) {
  __shared__ f16x8 EHs[2048];   // 2 x 16KB double buffer

  const int tid  = threadIdx.x;
  const int w    = tid >> 6;
  const int lane = tid & 63;
  const int tl   = lane & 15;
  const int gh   = lane >> 4;
  const int bid  = blockIdx.x;
  const int rb   = bid >> 2;       // row-block 0..255
  const int sp   = bid & 3;        // code split 0..3
  const int m0   = rb * BM;

  // resident A: 2 row-tiles x 16 K-chunks of f16x8 (zh only; e-conversion noise
  // dominates anyway, TAU-refine covers it)
  f16x8 zh[2][16];
#pragma unroll
  for (int rt = 0; rt < 2; ++rt) {
    const float* zp = z + (size_t)(m0 + w * 32 + rt * 16 + tl) * DIM + gh * 8;
#pragma unroll
    for (int c = 0; c < 16; ++c) {
      float4 a = *(const float4*)(zp + c * 32);
      float4 b = *(const float4*)(zp + c * 32 + 4);
      float f[8] = {a.x, a.y, a.z, a.w, b.x, b.y, b.z, b.w};
      f16x8 h;
#pragma unroll
      for (int j = 0; j < 8; ++j) h[j] = (_Float16)f[j];
      zh[rt][c] = h;
    }
  }

  float R1[8], R2[8], R3[8];
  int   I1[8], I2[8], I3[8];
#pragma unroll
  for (int i = 0; i < 8; ++i) {
    R1[i] = -INFINITY; R2[i] = -INFINITY; R3[i] = -INFINITY;
    I1[i] = 0x7fffffff; I2[i] = 0x7fffffff; I3[i] = 0x7fffffff;
  }

  const f16x8* tbase = img + (size_t)sp * 64 * 1024;  // this split's 64 tiles

  // prologue: stage tile 0 into buf 0 (each wave its 4KB quarter)
  {
    const char* g = (const char*)tbase + w * 4096 + lane * 16;
    char* l = (char*)EHs + w * 4096;
#pragma unroll
    for (int i = 0; i < 4; ++i) gload16(g + i * 1024, l + i * 1024);
  }
  __syncthreads();

  for (int kcl = 0; kcl < KCL; ++kcl) {
    f32x4 acc[2][4];
#pragma unroll
    for (int ct = 0; ct < 4; ++ct) {
      float nh = negHalf[sp * CPS + kcl * 64 + ct * 16 + tl];
      acc[0][ct] = (f32x4){nh, nh, nh, nh};
      acc[1][ct] = (f32x4){nh, nh, nh, nh};
    }

#pragma unroll
    for (int dci = 0; dci < 4; ++dci) {
      const int t = kcl * 4 + dci;
      const int cur = t & 1;
      if (t + 1 < 64) {  // stage next tile into the other buffer
        const char* g = (const char*)(tbase + (size_t)(t + 1) * 1024) + w * 4096 + lane * 16;
        char* l = (char*)EHs + (cur ^ 1) * 16384 + w * 4096;
#pragma unroll
        for (int i = 0; i < 4; ++i) gload16(g + i * 1024, l + i * 1024);
      }
      const f16x8* B = EHs + cur * 1024;
      // B-fragments in pairs (keeps live VGPRs lower than 4-wide)
#pragma unroll
      for (int ks = 0; ks < 4; ++ks) {
        {
          f16x8 bf0 = B[(ks * 4 + 0) * 64 + lane];
          f16x8 bf1 = B[(ks * 4 + 1) * 64 + lane];
          acc[0][0] = __builtin_amdgcn_mfma_f32_16x16x32_f16(zh[0][dci * 4 + ks], bf0, acc[0][0], 0, 0, 0);
          acc[1][0] = __builtin_amdgcn_mfma_f32_16x16x32_f16(zh[1][dci * 4 + ks], bf0, acc[1][0], 0, 0, 0);
          acc[0][1] = __builtin_amdgcn_mfma_f32_16x16x32_f16(zh[0][dci * 4 + ks], bf1, acc[0][1], 0, 0, 0);
          acc[1][1] = __builtin_amdgcn_mfma_f32_16x16x32_f16(zh[1][dci * 4 + ks], bf1, acc[1][1], 0, 0, 0);
        }
        {
          f16x8 bf2 = B[(ks * 4 + 2) * 64 + lane];
          f16x8 bf3 = B[(ks * 4 + 3) * 64 + lane];
          acc[0][2] = __builtin_amdgcn_mfma_f32_16x16x32_f16(zh[0][dci * 4 + ks], bf2, acc[0][2], 0, 0, 0);
          acc[1][2] = __builtin_amdgcn_mfma_f32_16x16x32_f16(zh[1][dci * 4 + ks], bf2, acc[1][2], 0, 0, 0);
          acc[0][3] = __builtin_amdgcn_mfma_f32_16x16x32_f16(zh[0][dci * 4 + ks], bf3, acc[0][3], 0, 0, 0);
          acc[1][3] = __builtin_amdgcn_mfma_f32_16x16x32_f16(zh[1][dci * 4 + ks], bf3, acc[1][3], 0, 0, 0);
        }
      }
      __syncthreads();
    }

    // merge the chunk's candidates (increasing code index -> strict '>' keeps
    // lowest index on exact ties)
#pragma unroll
    for (int rt = 0; rt < 2; ++rt)
#pragma unroll
      for (int ct = 0; ct < 4; ++ct) {
        int c = sp * CPS + kcl * 64 + ct * 16 + tl;
#pragma unroll
        for (int i = 0; i < 4; ++i) {
          int r8 = rt * 4 + i;
          float v = acc[rt][ct][i];
          if (v > R3[r8]) {
            if (v > R1[r8]) {
              R3[r8] = R2[r8]; I3[r8] = I2[r8];
              R2[r8] = R1[r8]; I2[r8] = I1[r8];
              R1[r8] = v;      I1[r8] = c;
            } else if (v > R2[r8]) {
              R3[r8] = R2[r8]; I3[r8] = I2[r8];
              R2[r8] = v;      I2[r8] = c;
            } else {
              R3[r8] = v;      I3[r8] = c;
            }
          }
        }
      }
  }

  // butterfly top-3 merge across the 16 tl-lanes (disjoint code sets)
#pragma unroll
  for (int m = 1; m < 16; m <<= 1) {
#pragma unroll
    for (int i = 0; i < 8; ++i) {
      float b1 = __shfl_xor(R1[i], m, 16); int j1 = __shfl_xor(I1[i], m, 16);
      float b2 = __shfl_xor(R2[i], m, 16); int j2 = __shfl_xor(I2[i], m, 16);
      float b3 = __shfl_xor(R3[i], m, 16); int j3 = __shfl_xor(I3[i], m, 16);
#pragma unroll
      for (int q = 0; q < 3; ++q) {
        float v = (q == 0) ? b1 : (q == 1) ? b2 : b3;
        int   c = (q == 0) ? j1 : (q == 1) ? j2 : j3;
        if (lexGT(v, c, R3[i], I3[i])) {
          if (lexGT(v, c, R1[i], I1[i])) {
            R3[i] = R2[i]; I3[i] = I2[i];
            R2[i] = R1[i]; I2[i] = I1[i];
            R1[i] = v;     I1[i] = c;
          } else if (lexGT(v, c, R2[i], I2[i])) {
            R3[i] = R2[i]; I3[i] = I2[i];
            R2[i] = v;     I2[i] = c;
          } else {
            R3[i] = v;     I3[i] = c;
          }
        }
      }
    }
  }

  if (tl == 0) {
#pragma unroll
    for (int i = 0; i < 8; ++i) {
      int row = m0 + w * 32 + (i >> 2) * 16 + gh * 4 + (i & 3);
      size_t pb = ((size_t)sp * N_ROWS + row) * 3;
      pscore[pb + 0] = R1[i]; pidx[pb + 0] = I1[i];
      pscore[pb + 1] = R2[i]; pidx[pb + 1] = I2[i];
      pscore[pb + 2] = R3[i]; pidx[pb + 2] = I3[i];
    }
  }
}

// ---- merge 4 split top-3s per row; np-exact refine on near-ties ----
__global__ __launch_bounds__(256) void vq_merge(const float* __restrict__ z,
                                                const float* __restrict__ emb,
                                                const float* __restrict__ Enp,
                                                const float* __restrict__ pscore,
                                                const int* __restrict__ pidx,
                                                int* __restrict__ bi,
                                                float* __restrict__ outIdx) {
  int row = blockIdx.x * 256 + threadIdx.x;
  float vs[12]; int cs[12];
#pragma unroll
  for (int s = 0; s < 4; ++s) {
    size_t pb = ((size_t)s * N_ROWS + row) * 3;
#pragma unroll
    for (int q = 0; q < 3; ++q) { vs[s * 3 + q] = pscore[pb + q]; cs[s * 3 + q] = pidx[pb + q]; }
  }
  float R1 = -INFINITY, R2 = -INFINITY; int i1 = 0x7fffffff;
#pragma unroll
  for (int j = 0; j < 12; ++j) {
    float v = vs[j]; int c = cs[j];
    if (lexGT(v, c, R1, i1)) { R2 = R1; R1 = v; i1 = c; }
    else if (v > R2) { R2 = v; }
  }
  int best = i1;
  if (R1 - R2 < TAU) {
#pragma clang fp contract(off)
    const float* zr = z + (size_t)row * DIM;
    float S = np_sumsq_512(zr);
    float bd = INFINITY; int bc = 0x7fffffff;
#pragma unroll 1
    for (int j = 0; j < 12; ++j) {
      if (R1 - vs[j] < TAU) {
        int c = cs[j];
        float D = np_dot_512(zr, emb + (size_t)c * DIM);
        float t = S + Enp[c];
        float d = t - 2.0f * D;
        if (d < bd || (d == bd && c < bc)) { bd = d; bc = c; }
      }
    }
    best = bc;
  }
  bi[row] = best;
  outIdx[row] = (float)best;
}

// ---- epilogue: gather e[best], write quantized, loss partials ----
__global__ __launch_bounds__(256) void vq_epi(const float* __restrict__ z,
                                              const float* __restrict__ emb,
                                              const int* __restrict__ bi,
                                              float* __restrict__ out,
                                              float* __restrict__ blockSums) {
  __shared__ float wred[4];
  int tid = threadIdx.x;
  int g = tid >> 4, tl = tid & 15;
  int row = blockIdx.x * 16 + g;
  const float* zr = z + (size_t)row * DIM;
  const float* er = emb + (size_t)bi[row] * DIM;
  float* oq = out + 1 + (size_t)row * DIM;
  float ls = 0.f;
#pragma unroll
  for (int j = 0; j < 8; ++j) {
    int d0 = (j * 16 + tl) * 4;
    float4 e = *(const float4*)(er + d0);
    float4 zz = *(const float4*)(zr + d0);
    float dx = e.x - zz.x, dy = e.y - zz.y, dz = e.z - zz.z, dw = e.w - zz.w;
    ls = fmaf(dx, dx, ls); ls = fmaf(dy, dy, ls);
    ls = fmaf(dz, dz, ls); ls = fmaf(dw, dw, ls);
    oq[d0 + 0] = e.x; oq[d0 + 1] = e.y; oq[d0 + 2] = e.z; oq[d0 + 3] = e.w;
  }
#pragma unroll
  for (int m = 1; m < 64; m <<= 1) ls += __shfl_xor(ls, m, 64);
  if ((tid & 63) == 0) wred[tid >> 6] = ls;
  __syncthreads();
  if (tid == 0) blockSums[blockIdx.x] = wred[0] + wred[1] + wred[2] + wred[3];
}

// loss = 1.25 * mean((q-z)^2); KL factor 0. 2048 partials.
__global__ __launch_bounds__(256) void vq_final(const float* __restrict__ blockSums,
                                                float* __restrict__ out) {
  __shared__ float red[256];
  int t = threadIdx.x;
  float s = 0.f;
#pragma unroll
  for (int i = 0; i < 8; ++i) s += blockSums[t + i * 256];
  red[t] = s;
  __syncthreads();
  for (int k = 128; k > 0; k >>= 1) {
    if (t < k) red[t] += red[t + k];
    __syncthreads();
  }
  if (t == 0) out[0] = red[0] * (1.25f / 16777216.0f);
}

extern "C" void kernel_launch(void* const* d_in, const int* in_sizes, int n_in,
                              void* d_out, int out_size, void* d_ws, size_t ws_size,
                              hipStream_t stream) {
  const float* z   = (const float*)d_in[0];
  const float* emb = (const float*)d_in[1];
  float* out  = (float*)d_out;
  float* wsf  = (float*)d_ws;
  f16x8* img      = (f16x8*)d_ws;
  float* negHalf  = wsf + OFF_NH;
  float* Enp      = wsf + OFF_EN;
  float* pscore   = wsf + OFF_PS;
  int*   pidx     = (int*)(wsf + OFF_PI);
  int*   bi       = (int*)(wsf + OFF_BI);
  float* bsums    = wsf + OFF_BS;
  float* outIdx   = out + 1 + (size_t)N_ROWS * DIM;
  (void)in_sizes; (void)n_in; (void)out_size; (void)ws_size;

  vq_prep_e  <<<KCODES / 256, 256, 0, stream>>>(emb, Enp, negHalf);
  vq_prep_img<<<1024, 256, 0, stream>>>(emb, img);
  vq_main    <<<1024, 256, 0, stream>>>(z, img, negHalf, pscore, pidx);
  vq_merge   <<<N_ROWS / 256, 256, 0, stream>>>(z, emb, Enp, pscore, pidx, bi, outIdx);
  vq_epi     <<<N_ROWS / 16, 256, 0, stream>>>(z, emb, bi, out, bsums);
  vq_final   <<<1, 256, 0, stream>>>(bsums, out);
}